// Round 12
// baseline (156.921 us; speedup 1.0000x reference)
//
#include <hip/hip_runtime.h>
#include <hip/hip_bf16.h>

typedef short s8v __attribute__((ext_vector_type(8)));      // 8 bf16 (4 VGPRs) MFMA A/B frag
typedef float f4v __attribute__((ext_vector_type(4)));      // MFMA C/D frag
typedef unsigned u4v __attribute__((ext_vector_type(4)));   // 4 packed bf16-pairs

__device__ __forceinline__ unsigned short f2bf(float x) {  // RTNE fp32->bf16 (prep only)
  unsigned u = __builtin_bit_cast(unsigned, x);
  u += 0x7fffu + ((u >> 16) & 1u);
  return (unsigned short)(u >> 16);
}
// pack 2 fp32 -> packed bf16 pair {lo=a, hi=b}
#if __has_builtin(__builtin_amdgcn_cvt_pk_bf16_f32)
__device__ __forceinline__ unsigned pk2(float a, float b) {
  return __builtin_bit_cast(unsigned, __builtin_amdgcn_cvt_pk_bf16_f32(a, b));
}
#else
__device__ __forceinline__ unsigned pk2(float a, float b) {  // 3 VALU ops, round-away
  unsigned ua = __builtin_bit_cast(unsigned, a) + 0x8000u;
  unsigned ub = __builtin_bit_cast(unsigned, b) + 0x8000u;
  return __builtin_amdgcn_perm(ub, ua, 0x07060302u);  // {ub.hi16, ua.hi16}
}
#endif

// async global->LDS DMA, 16 B per lane; LDS dest = wave-uniform base + lane*16
__device__ __forceinline__ void g2lds16(const void* g, void* l) {
  __builtin_amdgcn_global_load_lds(
      (const __attribute__((address_space(1))) unsigned*)g,
      (__attribute__((address_space(3))) unsigned*)l, 16, 0, 0);
}

// ---------------- prep: W1f/W2f fragment packs + latent->bf16 table ----------------
// ws layout (unsigned short): [0,8192) W1f, [8192,24576) W2f, [24576,+524288) latbf.
// W1f (8192): frag (h,ks): A[m=16h+l15][k=32ks+8q4+j]; k<13 -> W1 row k; k==13 -> b1;
//   14..15 -> 0; k>=16 -> W1 row k-3.
// W2f (16384): frag (h2,ks), K-permuted to match GEMM1-output register order:
//   k-slot 8q4+j (j<4) -> hidden 32ks+4q4+j ; (j>=4) -> hidden 32ks+16+4q4+(j-4).
__global__ void prep_kernel(const float* __restrict__ W1, const float* __restrict__ b1,
                            const float* __restrict__ W2, const float* __restrict__ latent,
                            unsigned short* __restrict__ wsW) {
  int e = blockIdx.x * 256 + threadIdx.x;   // 2144*256 = 548,864 = 24576 + 524288
  if (e < 8192) {
    int frag = e >> 9, rem = e & 511, lane = rem >> 3, j = rem & 7;
    int h = frag >> 1, ks = frag & 1;
    int q4 = lane >> 4, l15 = lane & 15;
    int k = ks * 32 + q4 * 8 + j;
    int n = h * 16 + l15;
    float v;
    if (k < 13) v = W1[k * 128 + n];
    else if (k == 13) v = b1[n];
    else if (k < 16) v = 0.0f;
    else v = W1[(k - 3) * 128 + n];
    wsW[e] = f2bf(v);
  } else if (e < 24576) {
    int e2 = e - 8192;
    int frag = e2 >> 9, rem = e2 & 511, lane = rem >> 3, j = rem & 7;
    int h2 = frag >> 2, ks = frag & 3;
    int q4 = lane >> 4, l15 = lane & 15;
    int kd = (j < 4) ? (32 * ks + 4 * q4 + j) : (32 * ks + 16 + 4 * q4 + (j - 4));
    int n = h2 * 16 + l15;
    wsW[e] = f2bf(W2[kd * 128 + n]);
  } else {
    int i = e - 24576;                      // latent -> bf16 (coalesced)
    wsW[e] = f2bf(latent[i]);
  }
}

// ---------------- main fused kernel ----------------
// 256 threads = 4 waves; each WG processes 4 tiles of 256 rows (grid 512, ~2 WG/CU).
// Software pipeline: tile i+1's gather (coord -> idx -> latbf) is issued into REGISTERS
// right after tile i's Bf reads, hiding the dependent gather chain behind tile i's GEMM
// (the per-WG serial chain R6-R10 showed is the plateau). W2f staged to LDS ONCE per WG
// via global_load_lds. AREA via same-wave __shfl (no LDS rewrite race in the pipeline).
// (256,2): tighter bounds trigger the gfx950 50/50 arch/acc split + scratch spill
// (R4/R5: reported VGPR == budget/2, WRITE_SIZE 66-700 MB).
__global__ __launch_bounds__(256, 2) void lisagon_main(
    const float* __restrict__ coord, const unsigned short* __restrict__ latbf,
    const unsigned short* __restrict__ W1f, const unsigned short* __restrict__ W2f,
    const float* __restrict__ b2, const float* __restrict__ W3,
    const float* __restrict__ b3, float* __restrict__ out) {
  __shared__ __align__(16) unsigned short A1[256 * 64];    // 32 KB input tile
  __shared__ __align__(16) unsigned short W2s[16384];      // 32 KB W2 fragments

  const int t = threadIdx.x;
  const int lane = t & 63, wv = t >> 6;
  const int l15 = lane & 15, q4 = lane >> 4;
  const int wgRow = blockIdx.x * 1024;       // 4 tiles x 256 rows per WG

  // ---- W2f -> LDS DMA, once per WG (drained by the first barrier) ----
#pragma unroll
  for (int it = 0; it < 8; it++) {
    int off = (it * 4 + wv) * 1024;          // bytes; wave-uniform LDS base
    g2lds16((const char*)W2f + off + lane * 16, (char*)W2s + off);
  }

  // ---- register prefetch state ----
  uint4 pL0[3], pL1[3];      // 3 latent rows (bf16, 32 B each)
  unsigned pPE[8];           // PE chunks 0..1 packed
  float pArea;

  auto do_prefetch = [&](int Rg) {
    const int gq = Rg >> 1, p = Rg & 1;      // p=0 -> vx=-2 pass, p=1 -> vx=0 pass
    const float co = coord[gq];
    float c = (co + (p ? 0.0f : -0.000244140625f)) + 1e-6f;  // vx*rx exact
    c = fminf(fmaxf(c, -1.0f + 1e-6f), 1.0f - 1e-6f);
    double u = ((double)c * 8192.0 + 8191.0) * 0.5;          // exact searchsorted
    int idx = (int)ceil(u);
    idx = min(max(idx, 0), 8191);
    const uint4* latv = (const uint4*)latbf + (size_t)(gq >> 16) * 16384;
    int r0 = max(idx - 1, 0), r2 = min(idx + 1, 8191);
    pL0[0] = latv[r0 * 2];  pL1[0] = latv[r0 * 2 + 1];
    pL0[1] = latv[idx * 2]; pL1[1] = latv[idx * 2 + 1];
    pL0[2] = latv[r2 * 2];  pL1[2] = latv[r2 * 2 + 1];
    float qc = ((float)(2 * idx + 1) - 8192.0f) * (1.0f / 8192.0f);  // exact grid[idx]
    float rel = (co - qc) * 8192.0f;
    pArea = fabsf(rel) + 1e-9f;
    float v[16];
    v[0] = rel;
    float f = rel;
#pragma unroll
    for (int i = 0; i < 6; i++) {
      v[1 + 2 * i] = __sinf(f);
      v[2 + 2 * i] = __cosf(f);
      f = f + f;               // exact power-of-2 freqs
    }
    v[13] = 1.0f;              // bias-fold slot (W1f input dim 13 = b1)
    v[14] = 0.0f; v[15] = 0.0f;
#pragma unroll
    for (int w = 0; w < 8; w++) pPE[w] = pk2(v[2 * w], v[2 * w + 1]);
  };

  do_prefetch(wgRow + t);      // tile 0

  const s8v* W1fv = (const s8v*)W1f;
  const s8v* W2sv = (const s8v*)W2s;
  const s8v* A1s  = (const s8v*)A1;
  const int rbase = wv * 64;
  const float b3s = b3[0];

  for (int tile = 0; tile < 4; tile++) {
    // ---- commit prefetched row to LDS (XOR-swizzled) ----
    const float myArea = pArea;
    {
      const int r = t;
      uint4* A1v = (uint4*)A1;
      uint4 q0, q1;
      q0.x = pPE[0]; q0.y = pPE[1]; q0.z = pPE[2]; q0.w = pPE[3];
      q1.x = pPE[4]; q1.y = pPE[5]; q1.z = pPE[6]; q1.w = pPE[7];
      A1v[r * 8 + (0 ^ (r & 7))] = q0;
      A1v[r * 8 + (1 ^ (r & 7))] = q1;
#pragma unroll
      for (int s = 0; s < 3; s++) {
        int ch0 = 2 + 2 * s;
        A1v[r * 8 + (ch0 ^ (r & 7))]       = pL0[s];
        A1v[r * 8 + ((ch0 + 1) ^ (r & 7))] = pL1[s];
      }
    }
    __syncthreads();                         // A1 ready (tile 0: also drains W2f DMA)

    // ---- load the 8 input B-fragments ----
    s8v Bf[2][4];
#pragma unroll
    for (int ks = 0; ks < 2; ks++)
#pragma unroll
      for (int rt = 0; rt < 4; rt++) {
        int row = rbase + rt * 16 + l15;
        Bf[ks][rt] = A1s[row * 8 + ((ks * 4 + q4) ^ (row & 7))];
      }
    __syncthreads();                         // all Bf reads done -> A1 reusable

    // ---- issue next tile's gather NOW; latency hides behind this tile's GEMM ----
    if (tile + 1 < 4) do_prefetch(wgRow + (tile + 1) * 256 + t);

    // ---- GEMM1' (h-outer): relu+pack directly into GEMM2 B-fragment lanes ----
    u4v bbv[4][4];
#pragma unroll
    for (int h = 0; h < 8; h++) {
      f4v a[4];
#pragma unroll
      for (int rt = 0; rt < 4; rt++) a[rt] = (f4v){0.f, 0.f, 0.f, 0.f};
#pragma unroll
      for (int ks = 0; ks < 2; ks++) {
        s8v Af = W1fv[(h * 2 + ks) * 64 + lane];
#pragma unroll
        for (int rt = 0; rt < 4; rt++)
          a[rt] = __builtin_amdgcn_mfma_f32_16x16x32_bf16(Af, Bf[ks][rt], a[rt], 0, 0, 0);
      }
#pragma unroll
      for (int rt = 0; rt < 4; rt++) {
        bbv[rt][h >> 1][2 * (h & 1)]     = pk2(fmaxf(a[rt][0], 0.f), fmaxf(a[rt][1], 0.f));
        bbv[rt][h >> 1][2 * (h & 1) + 1] = pk2(fmaxf(a[rt][2], 0.f), fmaxf(a[rt][3], 0.f));
      }
    }

    // ---- GEMM2' (h2-outer, weights from LDS): b2 as acc-init; consume into dot ----
    float s[4] = {0.f, 0.f, 0.f, 0.f};
#pragma unroll
    for (int h2 = 0; h2 < 8; h2++) {
      f4v a2[4];
      f4v b2v = ((const f4v*)b2)[h2 * 4 + q4];   // element i -> hidden2 16h2+4q4+i
#pragma unroll
      for (int rt = 0; rt < 4; rt++) a2[rt] = b2v;
#pragma unroll
      for (int ks = 0; ks < 4; ks++) {
        s8v Af = W2sv[(h2 * 4 + ks) * 64 + lane];   // ds_read_b128, conflict-free
#pragma unroll
        for (int rt = 0; rt < 4; rt++)
          a2[rt] = __builtin_amdgcn_mfma_f32_16x16x32_bf16(
              Af, __builtin_bit_cast(s8v, bbv[rt][ks]), a2[rt], 0, 0, 0);
      }
      float4 w3v = ((const float4*)W3)[h2 * 4 + q4];
#pragma unroll
      for (int rt = 0; rt < 4; rt++) {
        s[rt] += fmaxf(a2[rt][0], 0.f) * w3v.x;
        s[rt] += fmaxf(a2[rt][1], 0.f) * w3v.y;
        s[rt] += fmaxf(a2[rt][2], 0.f) * w3v.z;
        s[rt] += fmaxf(a2[rt][3], 0.f) * w3v.w;
      }
    }

    // ---- layer-3 reduce + local-ensemble combine (area via same-wave shfl) ----
#pragma unroll
    for (int rt = 0; rt < 4; rt++) {
      float pred = s[rt];
      pred += __shfl_xor(pred, 16, 64);
      pred += __shfl_xor(pred, 32, 64);
      pred += b3s;
      float other = __shfl_xor(pred, 1, 64);   // (pass0, pass1) at adjacent l15
      float a0 = __shfl(myArea, rt * 16 + l15, 64);        // area of row rbase+rt*16+l15
      float a1 = __shfl(myArea, rt * 16 + l15 + 1, 64);
      if (q4 == 0 && (l15 & 1) == 0) {
        int row0 = rbase + rt * 16 + l15;
        float tot = a0 + a1;
        // local_ensemble swap: pred(vx=-2)*a1/tot + pred(vx=0)*a0/tot
        out[(wgRow + tile * 256 + row0) >> 1] = pred * (a1 / tot) + other * (a0 / tot);
      }
    }
  }
}

extern "C" void kernel_launch(void* const* d_in, const int* in_sizes, int n_in,
                              void* d_out, int out_size, void* d_ws, size_t ws_size,
                              hipStream_t stream) {
  const float* coord  = (const float*)d_in[0];
  const float* latent = (const float*)d_in[1];
  const float* W1 = (const float*)d_in[2];
  const float* b1 = (const float*)d_in[3];
  const float* W2 = (const float*)d_in[4];
  const float* b2 = (const float*)d_in[5];
  const float* W3 = (const float*)d_in[6];
  const float* b3 = (const float*)d_in[7];
  float* out = (float*)d_out;
  unsigned short* wsW = (unsigned short*)d_ws;   // W1f | W2f | latbf

  prep_kernel<<<2144, 256, 0, stream>>>(W1, b1, W2, latent, wsW);
  lisagon_main<<<512, 256, 0, stream>>>(coord, wsW + 24576, wsW, wsW + 8192,
                                        b2, W3, b3, out);
}

// Round 13
// 111.415 us; speedup vs baseline: 1.4084x; 1.4084x over previous
//
#include <hip/hip_runtime.h>
#include <hip/hip_bf16.h>

typedef short s8v __attribute__((ext_vector_type(8)));      // 8 bf16 (4 VGPRs) MFMA A/B frag
typedef float f4v __attribute__((ext_vector_type(4)));      // MFMA C/D frag
typedef unsigned u4v __attribute__((ext_vector_type(4)));   // 4 packed bf16-pairs

__device__ __forceinline__ unsigned short f2bf(float x) {  // RTNE fp32->bf16 (prep only)
  unsigned u = __builtin_bit_cast(unsigned, x);
  u += 0x7fffu + ((u >> 16) & 1u);
  return (unsigned short)(u >> 16);
}
// pack 2 fp32 -> packed bf16 pair {lo=a, hi=b}
#if __has_builtin(__builtin_amdgcn_cvt_pk_bf16_f32)
__device__ __forceinline__ unsigned pk2(float a, float b) {
  return __builtin_bit_cast(unsigned, __builtin_amdgcn_cvt_pk_bf16_f32(a, b));
}
#else
__device__ __forceinline__ unsigned pk2(float a, float b) {  // 3 VALU ops, round-away
  unsigned ua = __builtin_bit_cast(unsigned, a) + 0x8000u;
  unsigned ub = __builtin_bit_cast(unsigned, b) + 0x8000u;
  return __builtin_amdgcn_perm(ub, ua, 0x07060302u);  // {ub.hi16, ua.hi16}
}
#endif

// async global->LDS DMA, 16 B per lane. Per-lane GLOBAL address (gather) is fine;
// LDS dest is wave-uniform base, lane i lands at base + i*16 (m104/m108).
__device__ __forceinline__ void g2lds16(const void* g, void* l) {
  __builtin_amdgcn_global_load_lds(
      (const __attribute__((address_space(1))) unsigned*)g,
      (__attribute__((address_space(3))) unsigned*)l, 16, 0, 0);
}

// ---------------- prep: W1f/W2f fragment packs + latent->bf16 table ----------------
// ws layout (unsigned short): [0,8192) W1f, [8192,24576) W2f, [24576,+524288) latbf.
// W1f (8192): frag (h,ks): A[m=16h+l15][k=32ks+8q4+j]; k<13 -> W1 row k; k==13 -> b1;
//   14..15 -> 0; k>=16 -> W1 row k-3.
// W2f (16384): frag (h2,ks), K-permuted to match GEMM1-output register order:
//   k-slot 8q4+j (j<4) -> hidden 32ks+4q4+j ; (j>=4) -> hidden 32ks+16+4q4+(j-4).
__global__ void prep_kernel(const float* __restrict__ W1, const float* __restrict__ b1,
                            const float* __restrict__ W2, const float* __restrict__ latent,
                            unsigned short* __restrict__ wsW) {
  int e = blockIdx.x * 256 + threadIdx.x;   // 2144*256 = 548,864 = 24576 + 524288
  if (e < 8192) {
    int frag = e >> 9, rem = e & 511, lane = rem >> 3, j = rem & 7;
    int h = frag >> 1, ks = frag & 1;
    int q4 = lane >> 4, l15 = lane & 15;
    int k = ks * 32 + q4 * 8 + j;
    int n = h * 16 + l15;
    float v;
    if (k < 13) v = W1[k * 128 + n];
    else if (k == 13) v = b1[n];
    else if (k < 16) v = 0.0f;
    else v = W1[(k - 3) * 128 + n];
    wsW[e] = f2bf(v);
  } else if (e < 24576) {
    int e2 = e - 8192;
    int frag = e2 >> 9, rem = e2 & 511, lane = rem >> 3, j = rem & 7;
    int h2 = frag >> 2, ks = frag & 3;
    int q4 = lane >> 4, l15 = lane & 15;
    int kd = (j < 4) ? (32 * ks + 4 * q4 + j) : (32 * ks + 16 + 4 * q4 + (j - 4));
    int n = h2 * 16 + l15;
    wsW[e] = f2bf(W2[kd * 128 + n]);
  } else {
    int i = e - 24576;                      // latent -> bf16 (coalesced)
    wsW[e] = f2bf(latent[i]);
  }
}

// ---------------- main fused kernel ----------------
// 256 threads = 4 waves; WG processes 4 tiles of 256 rows (grid 512, 1 WG/CU by LDS).
// A1 double-buffered, CHUNK-MAJOR (plane ch = 16B chunk ch of all 256 rows): next
// tile's latent gather goes straight global->LDS via global_load_lds (per-lane global
// gather address, LDS dest = plane + wv*1024 + lane*16 = row*16). ZERO register
// prefetch state (R12's register pipeline spilled: VGPR==budget/2, WRITE 59 MB).
// PE chunks are VALU-computed and ds_written in the same spot. One barrier per tile.
// (256,1): loose bound avoids the gfx950 tight-bound arch/acc split + spill.
__global__ __launch_bounds__(256, 1) void lisagon_main(
    const float* __restrict__ coord, const unsigned short* __restrict__ latbf,
    const unsigned short* __restrict__ W1f, const unsigned short* __restrict__ W2f,
    const float* __restrict__ b2, const float* __restrict__ W3,
    const float* __restrict__ b3, float* __restrict__ out) {
  __shared__ __align__(16) unsigned short A1[2][8][2048];  // 2 bufs x 8 planes x 4 KB
  __shared__ __align__(16) unsigned short W2s[16384];      // 32 KB W2 fragments

  const int t = threadIdx.x;
  const int lane = t & 63, wv = t >> 6;
  const int l15 = lane & 15, q4 = lane >> 4;
  const int wgRow = blockIdx.x * 1024;       // 4 tiles x 256 rows per WG

  // ---- W2f -> LDS DMA, once per WG ----
#pragma unroll
  for (int it = 0; it < 8; it++) {
    int off = (it * 4 + wv) * 1024;          // bytes; wave-uniform LDS base
    g2lds16((const char*)W2f + off + lane * 16, (char*)W2s + off);
  }

  // ---- all 4 tile coords up front (4 VGPRs; kills the coord-load latency link) ----
  float co4[4];
#pragma unroll
  for (int i = 0; i < 4; i++) co4[i] = coord[(wgRow + i * 256 + t) >> 1];

  float areaNext;
  // prefetch tile data for global row Rg into buffer nb (NO registers held after)
  auto prefetch = [&](int tileIdx, int nb) {
    const int Rg = wgRow + tileIdx * 256 + t;
    const int gq = Rg >> 1, p = Rg & 1;      // p=0 -> vx=-2 pass, p=1 -> vx=0 pass
    const float co = co4[tileIdx];
    float c = (co + (p ? 0.0f : -0.000244140625f)) + 1e-6f;  // vx*rx exact
    c = fminf(fmaxf(c, -1.0f + 1e-6f), 1.0f - 1e-6f);
    double u = ((double)c * 8192.0 + 8191.0) * 0.5;          // exact searchsorted
    int idx = (int)ceil(u);
    idx = min(max(idx, 0), 8191);

    // latent gather straight to LDS planes 2..7 (prev/self/next, 2 planes each)
    const char* base = (const char*)(latbf + (size_t)(gq >> 16) * (8192 * 16));
    const char* r0 = base + (size_t)max(idx - 1, 0) * 32;
    const char* r1 = base + (size_t)idx * 32;
    const char* r2 = base + (size_t)min(idx + 1, 8191) * 32;
    char* pl = (char*)A1[nb][0] + wv * 1024;   // plane stride 4096 B
    g2lds16(r0,      pl + 2 * 4096);
    g2lds16(r0 + 16, pl + 3 * 4096);
    g2lds16(r1,      pl + 4 * 4096);
    g2lds16(r1 + 16, pl + 5 * 4096);
    g2lds16(r2,      pl + 6 * 4096);
    g2lds16(r2 + 16, pl + 7 * 4096);

    float qc = ((float)(2 * idx + 1) - 8192.0f) * (1.0f / 8192.0f);  // exact grid[idx]
    float rel = (co - qc) * 8192.0f;
    areaNext = fabsf(rel) + 1e-9f;

    float v[16];
    v[0] = rel;
    float f = rel;
#pragma unroll
    for (int i = 0; i < 6; i++) {
      v[1 + 2 * i] = __sinf(f);
      v[2 + 2 * i] = __cosf(f);
      f = f + f;               // exact power-of-2 freqs
    }
    v[13] = 1.0f;              // bias-fold slot (W1f input dim 13 = b1)
    v[14] = 0.0f; v[15] = 0.0f;
    uint4 q0, q1;
    q0.x = pk2(v[0], v[1]);  q0.y = pk2(v[2], v[3]);
    q0.z = pk2(v[4], v[5]);  q0.w = pk2(v[6], v[7]);
    q1.x = pk2(v[8], v[9]);  q1.y = pk2(v[10], v[11]);
    q1.z = pk2(v[12], v[13]); q1.w = pk2(v[14], v[15]);
    ((uint4*)A1[nb][0])[t] = q0;             // PE planes 0,1: thread t -> slot t
    ((uint4*)A1[nb][1])[t] = q1;
  };

  prefetch(0, 0);              // tile 0 into buffer 0

  const s8v* W1fv = (const s8v*)W1f;
  const s8v* W2sv = (const s8v*)W2s;
  const int rbase = wv * 64;
  const float b3s = b3[0];

  for (int tile = 0; tile < 4; tile++) {
    const int cur = tile & 1;
    const float areaCur = areaNext;
    __syncthreads();   // drains DMA/ds_writes into buf cur; fences buf cur^1 reuse

    // ---- Bf reads (chunk-major: plane ks*4+q4, row rbase+rt*16+l15) ----
    const s8v* bufS = (const s8v*)A1[cur][0];   // plane p at p*256 (s8v units)
    s8v Bf[2][4];
#pragma unroll
    for (int ks = 0; ks < 2; ks++)
#pragma unroll
      for (int rt = 0; rt < 4; rt++)
        Bf[ks][rt] = bufS[(ks * 4 + q4) * 256 + rbase + rt * 16 + l15];

    // ---- issue next tile's gather into the other buffer (hides behind GEMM) ----
    if (tile + 1 < 4) prefetch(tile + 1, cur ^ 1);

    // ---- GEMM1' (h-outer): relu+pack directly into GEMM2 B-fragment lanes ----
    u4v bbv[4][4];
#pragma unroll
    for (int h = 0; h < 8; h++) {
      f4v a[4];
#pragma unroll
      for (int rt = 0; rt < 4; rt++) a[rt] = (f4v){0.f, 0.f, 0.f, 0.f};
#pragma unroll
      for (int ks = 0; ks < 2; ks++) {
        s8v Af = W1fv[(h * 2 + ks) * 64 + lane];
#pragma unroll
        for (int rt = 0; rt < 4; rt++)
          a[rt] = __builtin_amdgcn_mfma_f32_16x16x32_bf16(Af, Bf[ks][rt], a[rt], 0, 0, 0);
      }
#pragma unroll
      for (int rt = 0; rt < 4; rt++) {
        bbv[rt][h >> 1][2 * (h & 1)]     = pk2(fmaxf(a[rt][0], 0.f), fmaxf(a[rt][1], 0.f));
        bbv[rt][h >> 1][2 * (h & 1) + 1] = pk2(fmaxf(a[rt][2], 0.f), fmaxf(a[rt][3], 0.f));
      }
    }

    // ---- GEMM2' (h2-outer, weights from LDS): b2 as acc-init; consume into dot ----
    float s[4] = {0.f, 0.f, 0.f, 0.f};
#pragma unroll
    for (int h2 = 0; h2 < 8; h2++) {
      f4v a2[4];
      f4v b2v = ((const f4v*)b2)[h2 * 4 + q4];   // element i -> hidden2 16h2+4q4+i
#pragma unroll
      for (int rt = 0; rt < 4; rt++) a2[rt] = b2v;
#pragma unroll
      for (int ks = 0; ks < 4; ks++) {
        s8v Af = W2sv[(h2 * 4 + ks) * 64 + lane];   // ds_read_b128
#pragma unroll
        for (int rt = 0; rt < 4; rt++)
          a2[rt] = __builtin_amdgcn_mfma_f32_16x16x32_bf16(
              Af, __builtin_bit_cast(s8v, bbv[rt][ks]), a2[rt], 0, 0, 0);
      }
      float4 w3v = ((const float4*)W3)[h2 * 4 + q4];
#pragma unroll
      for (int rt = 0; rt < 4; rt++) {
        s[rt] += fmaxf(a2[rt][0], 0.f) * w3v.x;
        s[rt] += fmaxf(a2[rt][1], 0.f) * w3v.y;
        s[rt] += fmaxf(a2[rt][2], 0.f) * w3v.z;
        s[rt] += fmaxf(a2[rt][3], 0.f) * w3v.w;
      }
    }

    // ---- layer-3 reduce + local-ensemble combine (area via same-wave shfl) ----
#pragma unroll
    for (int rt = 0; rt < 4; rt++) {
      float pred = s[rt];
      pred += __shfl_xor(pred, 16, 64);
      pred += __shfl_xor(pred, 32, 64);
      pred += b3s;
      float other = __shfl_xor(pred, 1, 64);   // (pass0, pass1) at adjacent l15
      float a0 = __shfl(areaCur, rt * 16 + l15, 64);   // row rbase+rt*16+l15 = same wave
      float a1 = __shfl(areaCur, rt * 16 + l15 + 1, 64);
      if (q4 == 0 && (l15 & 1) == 0) {
        int row0 = rbase + rt * 16 + l15;
        float tot = a0 + a1;
        // local_ensemble swap: pred(vx=-2)*a1/tot + pred(vx=0)*a0/tot
        out[(wgRow + tile * 256 + row0) >> 1] = pred * (a1 / tot) + other * (a0 / tot);
      }
    }
  }
}

extern "C" void kernel_launch(void* const* d_in, const int* in_sizes, int n_in,
                              void* d_out, int out_size, void* d_ws, size_t ws_size,
                              hipStream_t stream) {
  const float* coord  = (const float*)d_in[0];
  const float* latent = (const float*)d_in[1];
  const float* W1 = (const float*)d_in[2];
  const float* b1 = (const float*)d_in[3];
  const float* W2 = (const float*)d_in[4];
  const float* b2 = (const float*)d_in[5];
  const float* W3 = (const float*)d_in[6];
  const float* b3 = (const float*)d_in[7];
  float* out = (float*)d_out;
  unsigned short* wsW = (unsigned short*)d_ws;   // W1f | W2f | latbf

  prep_kernel<<<2144, 256, 0, stream>>>(W1, b1, W2, latent, wsW);
  lisagon_main<<<512, 256, 0, stream>>>(coord, wsW + 24576, wsW, wsW + 8192,
                                        b2, W3, b3, out);
}

// Round 14
// 99.878 us; speedup vs baseline: 1.5711x; 1.1155x over previous
//
#include <hip/hip_runtime.h>
#include <hip/hip_bf16.h>

typedef short s8v __attribute__((ext_vector_type(8)));      // 8 bf16 (4 VGPRs) MFMA A/B frag
typedef float f4v __attribute__((ext_vector_type(4)));      // MFMA C/D frag
typedef unsigned u4v __attribute__((ext_vector_type(4)));   // 4 packed bf16-pairs

__device__ __forceinline__ unsigned short f2bf(float x) {  // RTNE fp32->bf16 (prep only)
  unsigned u = __builtin_bit_cast(unsigned, x);
  u += 0x7fffu + ((u >> 16) & 1u);
  return (unsigned short)(u >> 16);
}
// pack 2 fp32 -> packed bf16 pair {lo=a, hi=b}
#if __has_builtin(__builtin_amdgcn_cvt_pk_bf16_f32)
__device__ __forceinline__ unsigned pk2(float a, float b) {
  return __builtin_bit_cast(unsigned, __builtin_amdgcn_cvt_pk_bf16_f32(a, b));
}
#else
__device__ __forceinline__ unsigned pk2(float a, float b) {  // 3 VALU ops, round-away
  unsigned ua = __builtin_bit_cast(unsigned, a) + 0x8000u;
  unsigned ub = __builtin_bit_cast(unsigned, b) + 0x8000u;
  return __builtin_amdgcn_perm(ub, ua, 0x07060302u);  // {ub.hi16, ua.hi16}
}
#endif

// async global->LDS DMA, 16 B per lane; LDS dest = wave-uniform base + lane*16
__device__ __forceinline__ void g2lds16(const void* g, void* l) {
  __builtin_amdgcn_global_load_lds(
      (const __attribute__((address_space(1))) unsigned*)g,
      (__attribute__((address_space(3))) unsigned*)l, 16, 0, 0);
}

// ---------------- prep: W1f/W2f fragment packs + latent->bf16 table ----------------
// ws layout (unsigned short): [0,8192) W1f, [8192,24576) W2f, [24576,+524288) latbf.
// W1f (8192): frag (h,ks): A[m=16h+l15][k=32ks+8q4+j]; k<13 -> W1 row k; k==13 -> b1;
//   14..15 -> 0; k>=16 -> W1 row k-3.
// W2f (16384): frag (h2,ks), K-permuted to match GEMM1-output register order:
//   k-slot 8q4+j (j<4) -> hidden 32ks+4q4+j ; (j>=4) -> hidden 32ks+16+4q4+(j-4).
__global__ void prep_kernel(const float* __restrict__ W1, const float* __restrict__ b1,
                            const float* __restrict__ W2, const float* __restrict__ latent,
                            unsigned short* __restrict__ wsW) {
  int e = blockIdx.x * 256 + threadIdx.x;   // 2144*256 = 548,864 = 24576 + 524288
  if (e < 8192) {
    int frag = e >> 9, rem = e & 511, lane = rem >> 3, j = rem & 7;
    int h = frag >> 1, ks = frag & 1;
    int q4 = lane >> 4, l15 = lane & 15;
    int k = ks * 32 + q4 * 8 + j;
    int n = h * 16 + l15;
    float v;
    if (k < 13) v = W1[k * 128 + n];
    else if (k == 13) v = b1[n];
    else if (k < 16) v = 0.0f;
    else v = W1[(k - 3) * 128 + n];
    wsW[e] = f2bf(v);
  } else if (e < 24576) {
    int e2 = e - 8192;
    int frag = e2 >> 9, rem = e2 & 511, lane = rem >> 3, j = rem & 7;
    int h2 = frag >> 2, ks = frag & 3;
    int q4 = lane >> 4, l15 = lane & 15;
    int kd = (j < 4) ? (32 * ks + 4 * q4 + j) : (32 * ks + 16 + 4 * q4 + (j - 4));
    int n = h2 * 16 + l15;
    wsW[e] = f2bf(W2[kd * 128 + n]);
  } else {
    int i = e - 24576;                      // latent -> bf16 (coalesced)
    wsW[e] = f2bf(latent[i]);
  }
}

// ---------------- main fused kernel ----------------
// 256 threads = 4 waves. WG = 256 rows (128 queries x 2 passes); each wave owns 64 rows
// as 4 row-tiles (rt). Grid = 2048, 2 WG/CU (the best-measured overlap config, R11:
// ~9.9k cyc per 256-row tile). Delta vs R11: ZERO global loads after the barrier --
// W1f preloaded to 16 s8v registers (64 VGPRs; budget at (256,2) is 256, R11 used only
// 124), b2/W3 staged to LDS. Avoids all post-barrier vmcnt waits (R13 showed global
// loads entangle with DMA drains; L1/L2 latency was the residual stall).
// (256,2): tighter bounds trigger the gfx950 50/50 arch/acc split + scratch spill
// (R4/R5: reported VGPR == budget/2, WRITE_SIZE 66-700 MB).
__global__ __launch_bounds__(256, 2) void lisagon_main(
    const float* __restrict__ coord, const unsigned short* __restrict__ latbf,
    const unsigned short* __restrict__ W1f, const unsigned short* __restrict__ W2f,
    const float* __restrict__ b2, const float* __restrict__ W3,
    const float* __restrict__ b3, float* __restrict__ out) {
  __shared__ __align__(16) unsigned short A1[256 * 64];    // 32 KB input tile
  __shared__ __align__(16) unsigned short W2s[16384];      // 32 KB W2 fragments
  __shared__ float AREA[256];
  __shared__ __align__(16) float BW[256];                  // b2 [0,128) | W3 [128,256)

  const int t = threadIdx.x;
  const int lane = t & 63, wv = t >> 6;
  const int l15 = lane & 15, q4 = lane >> 4;

  // ---- issue W2f -> LDS DMA first ----
#pragma unroll
  for (int it = 0; it < 8; it++) {
    int off = (it * 4 + wv) * 1024;          // bytes; wave-uniform LDS base
    g2lds16((const char*)W2f + off + lane * 16, (char*)W2s + off);
  }

  // ---- preload all 16 W1f fragments into registers (loop-invariant, L1/L2-hot) ----
  const s8v* W1fv = (const s8v*)W1f;
  s8v W1r[16];
#pragma unroll
  for (int i = 0; i < 16; i++) W1r[i] = W1fv[i * 64 + lane];

  // ---- stage b2 / W3 into LDS (1 KB) ----
  if (t < 64) {
    ((float4*)BW)[t] = (t < 32) ? ((const float4*)b2)[t] : ((const float4*)W3)[t - 32];
  }

  // ---- phase 0: one full input row per thread (no divergence) ----
  {
    const int r = t;                          // local row 0..255
    const int Rg = blockIdx.x * 256 + r;
    const int gq = Rg >> 1, p = Rg & 1;       // p=0 -> vx=-2 pass, p=1 -> vx=0 pass
    const float co = coord[gq];
    float c = (co + (p ? 0.0f : -0.000244140625f)) + 1e-6f;  // vx*rx exact
    c = fminf(fmaxf(c, -1.0f + 1e-6f), 1.0f - 1e-6f);
    double u = ((double)c * 8192.0 + 8191.0) * 0.5;          // exact searchsorted
    int idx = (int)ceil(u);
    idx = min(max(idx, 0), 8191);

    float qc = ((float)(2 * idx + 1) - 8192.0f) * (1.0f / 8192.0f);  // exact grid[idx]
    float rel = (co - qc) * 8192.0f;
    AREA[r] = fabsf(rel) + 1e-9f;

    uint4* A1v = (uint4*)A1;
    // latent chunks 2..7: 3 bf16 rows (prev/self/next), 32 B each -- no conversion
    const uint4* latv = (const uint4*)(latbf + (size_t)(gq >> 16) * (8192 * 16));
    int rows3[3];
    rows3[0] = max(idx - 1, 0);
    rows3[1] = idx;
    rows3[2] = min(idx + 1, 8191);
    uint4 L0[3], L1[3];
#pragma unroll
    for (int s = 0; s < 3; s++) {
      L0[s] = latv[rows3[s] * 2 + 0];
      L1[s] = latv[rows3[s] * 2 + 1];
    }

    // PE chunks 0..1
    float v[16];
    v[0] = rel;
    float f = rel;
#pragma unroll
    for (int i = 0; i < 6; i++) {
      v[1 + 2 * i] = __sinf(f);
      v[2 + 2 * i] = __cosf(f);
      f = f + f;                 // exact power-of-2 freqs
    }
    v[13] = 1.0f;                // bias-fold slot (W1f input dim 13 = b1)
    v[14] = 0.0f; v[15] = 0.0f;
#pragma unroll
    for (int ch = 0; ch < 2; ch++) {
      union { uint4 u4; unsigned us[4]; } pkv;
#pragma unroll
      for (int w = 0; w < 4; w++) pkv.us[w] = pk2(v[ch * 8 + 2 * w], v[ch * 8 + 2 * w + 1]);
      A1v[r * 8 + (ch ^ (r & 7))] = pkv.u4;
    }
#pragma unroll
    for (int s = 0; s < 3; s++) {
      int ch0 = 2 + 2 * s;
      A1v[r * 8 + (ch0 ^ (r & 7))]       = L0[s];
      A1v[r * 8 + ((ch0 + 1) ^ (r & 7))] = L1[s];
    }
  }
  __syncthreads();   // drains W2f DMA + all LDS writes; NO global loads after this

  const s8v* W2sv = (const s8v*)W2s;
  const s8v* A1s  = (const s8v*)A1;
  const int rbase = wv * 64;

  // ---- load all 8 input B-fragments (live across GEMM1) ----
  s8v Bf[2][4];
#pragma unroll
  for (int ks = 0; ks < 2; ks++)
#pragma unroll
    for (int rt = 0; rt < 4; rt++) {
      int row = rbase + rt * 16 + l15;
      Bf[ks][rt] = A1s[row * 8 + ((ks * 4 + q4) ^ (row & 7))];
    }

  // ---- GEMM1' (h-outer): one h-tile acc live; relu+pack DIRECTLY into bbv lanes ----
  // bbv[rt][ks] is GEMM2's B-fragment for K-chunk ks (K-permuted to match W2f):
  //   lane 2h'+half holds packed pair from GEMM1 output h = 2ks+h', half in {0,1}.
  u4v bbv[4][4];
#pragma unroll
  for (int h = 0; h < 8; h++) {
    f4v a[4];
#pragma unroll
    for (int rt = 0; rt < 4; rt++) a[rt] = (f4v){0.f, 0.f, 0.f, 0.f};
#pragma unroll
    for (int ks = 0; ks < 2; ks++) {
#pragma unroll
      for (int rt = 0; rt < 4; rt++)
        a[rt] = __builtin_amdgcn_mfma_f32_16x16x32_bf16(W1r[h * 2 + ks], Bf[ks][rt],
                                                        a[rt], 0, 0, 0);
    }
#pragma unroll
    for (int rt = 0; rt < 4; rt++) {
      bbv[rt][h >> 1][2 * (h & 1)]     = pk2(fmaxf(a[rt][0], 0.f), fmaxf(a[rt][1], 0.f));
      bbv[rt][h >> 1][2 * (h & 1) + 1] = pk2(fmaxf(a[rt][2], 0.f), fmaxf(a[rt][3], 0.f));
    }
  }

  // ---- GEMM2' (h2-outer, weights from LDS): b2 as acc-init; consume into dot ----
  float s[4] = {0.f, 0.f, 0.f, 0.f};
#pragma unroll
  for (int h2 = 0; h2 < 8; h2++) {
    f4v a2[4];
    f4v b2v = ((const f4v*)BW)[h2 * 4 + q4];   // LDS broadcast; elem i -> h2dim 16h2+4q4+i
#pragma unroll
    for (int rt = 0; rt < 4; rt++) a2[rt] = b2v;
#pragma unroll
    for (int ks = 0; ks < 4; ks++) {
      s8v Af = W2sv[(h2 * 4 + ks) * 64 + lane];   // ds_read_b128, conflict-free
#pragma unroll
      for (int rt = 0; rt < 4; rt++)
        a2[rt] = __builtin_amdgcn_mfma_f32_16x16x32_bf16(
            Af, __builtin_bit_cast(s8v, bbv[rt][ks]), a2[rt], 0, 0, 0);
    }
    float4 w3v = ((const float4*)(BW + 128))[h2 * 4 + q4];   // LDS broadcast
#pragma unroll
    for (int rt = 0; rt < 4; rt++) {
      s[rt] += fmaxf(a2[rt][0], 0.f) * w3v.x;
      s[rt] += fmaxf(a2[rt][1], 0.f) * w3v.y;
      s[rt] += fmaxf(a2[rt][2], 0.f) * w3v.z;
      s[rt] += fmaxf(a2[rt][3], 0.f) * w3v.w;
    }
  }

  // ---- layer-3 reduce + local-ensemble combine ----
  const float b3s = b3[0];
#pragma unroll
  for (int rt = 0; rt < 4; rt++) {
    float pred = s[rt];
    pred += __shfl_xor(pred, 16, 64);
    pred += __shfl_xor(pred, 32, 64);
    pred += b3s;
    float other = __shfl_xor(pred, 1, 64);   // (pass0, pass1) at adjacent l15
    if (q4 == 0 && (l15 & 1) == 0) {
      int row0 = rbase + rt * 16 + l15;
      float a0 = AREA[row0], a1 = AREA[row0 + 1];
      float tot = a0 + a1;
      // local_ensemble swap: pred(vx=-2)*a1/tot + pred(vx=0)*a0/tot
      out[(blockIdx.x * 256 + row0) >> 1] = pred * (a1 / tot) + other * (a0 / tot);
    }
  }
}

extern "C" void kernel_launch(void* const* d_in, const int* in_sizes, int n_in,
                              void* d_out, int out_size, void* d_ws, size_t ws_size,
                              hipStream_t stream) {
  const float* coord  = (const float*)d_in[0];
  const float* latent = (const float*)d_in[1];
  const float* W1 = (const float*)d_in[2];
  const float* b1 = (const float*)d_in[3];
  const float* W2 = (const float*)d_in[4];
  const float* b2 = (const float*)d_in[5];
  const float* W3 = (const float*)d_in[6];
  const float* b3 = (const float*)d_in[7];
  float* out = (float*)d_out;
  unsigned short* wsW = (unsigned short*)d_ws;   // W1f | W2f | latbf

  prep_kernel<<<2144, 256, 0, stream>>>(W1, b1, W2, latent, wsW);
  lisagon_main<<<2048, 256, 0, stream>>>(coord, wsW + 24576, wsW, wsW + 8192,
                                         b2, W3, b3, out);
}

// Round 15
// 97.237 us; speedup vs baseline: 1.6138x; 1.0272x over previous
//
#include <hip/hip_runtime.h>
#include <hip/hip_bf16.h>

typedef short s8v __attribute__((ext_vector_type(8)));      // 8 bf16 (4 VGPRs) MFMA A/B frag
typedef float f4v __attribute__((ext_vector_type(4)));      // MFMA C/D frag
typedef unsigned u4v __attribute__((ext_vector_type(4)));   // 4 packed bf16-pairs

__device__ __forceinline__ unsigned short f2bf(float x) {  // RTNE fp32->bf16 (prep only)
  unsigned u = __builtin_bit_cast(unsigned, x);
  u += 0x7fffu + ((u >> 16) & 1u);
  return (unsigned short)(u >> 16);
}
// pack 2 fp32 -> packed bf16 pair {lo=a, hi=b}
#if __has_builtin(__builtin_amdgcn_cvt_pk_bf16_f32)
__device__ __forceinline__ unsigned pk2(float a, float b) {
  return __builtin_bit_cast(unsigned, __builtin_amdgcn_cvt_pk_bf16_f32(a, b));
}
#else
__device__ __forceinline__ unsigned pk2(float a, float b) {  // 3 VALU ops, round-away
  unsigned ua = __builtin_bit_cast(unsigned, a) + 0x8000u;
  unsigned ub = __builtin_bit_cast(unsigned, b) + 0x8000u;
  return __builtin_amdgcn_perm(ub, ua, 0x07060302u);  // {ub.hi16, ua.hi16}
}
#endif

// async global->LDS DMA, 16 B per lane; LDS dest = wave-uniform base + lane*16
__device__ __forceinline__ void g2lds16(const void* g, void* l) {
  __builtin_amdgcn_global_load_lds(
      (const __attribute__((address_space(1))) unsigned*)g,
      (__attribute__((address_space(3))) unsigned*)l, 16, 0, 0);
}

// ---------------- prep: W1f/W2f fragment packs + latent->bf16 table ----------------
// ws layout (unsigned short): [0,8192) W1f, [8192,24576) W2f, [24576,+524288) latbf.
// W1f (8192): frag (h,ks): A[m=16h+l15][k=32ks+8q4+j]; k<13 -> W1 row k; k==13 -> b1;
//   14..15 -> 0; k>=16 -> W1 row k-3.
// W2f (16384): frag (h2,ks), K-permuted to match GEMM1-output register order:
//   k-slot 8q4+j (j<4) -> hidden 32ks+4q4+j ; (j>=4) -> hidden 32ks+16+4q4+(j-4).
__global__ void prep_kernel(const float* __restrict__ W1, const float* __restrict__ b1,
                            const float* __restrict__ W2, const float* __restrict__ latent,
                            unsigned short* __restrict__ wsW) {
  int e = blockIdx.x * 256 + threadIdx.x;   // 2144*256 = 548,864 = 24576 + 524288
  if (e < 8192) {
    int frag = e >> 9, rem = e & 511, lane = rem >> 3, j = rem & 7;
    int h = frag >> 1, ks = frag & 1;
    int q4 = lane >> 4, l15 = lane & 15;
    int k = ks * 32 + q4 * 8 + j;
    int n = h * 16 + l15;
    float v;
    if (k < 13) v = W1[k * 128 + n];
    else if (k == 13) v = b1[n];
    else if (k < 16) v = 0.0f;
    else v = W1[(k - 3) * 128 + n];
    wsW[e] = f2bf(v);
  } else if (e < 24576) {
    int e2 = e - 8192;
    int frag = e2 >> 9, rem = e2 & 511, lane = rem >> 3, j = rem & 7;
    int h2 = frag >> 2, ks = frag & 3;
    int q4 = lane >> 4, l15 = lane & 15;
    int kd = (j < 4) ? (32 * ks + 4 * q4 + j) : (32 * ks + 16 + 4 * q4 + (j - 4));
    int n = h2 * 16 + l15;
    wsW[e] = f2bf(W2[kd * 128 + n]);
  } else {
    int i = e - 24576;                      // latent -> bf16 (coalesced)
    wsW[e] = f2bf(latent[i]);
  }
}

// ---------------- main fused kernel ----------------
// 256 threads = 4 waves; WG = 256 rows; wave wv owns rows [64wv,64wv+64) -- the SAME
// rows its threads phase-0 (thread t = row t). Grid 2048, 2 WG/CU.
// NO A1 staging: each lane assembles its B-fragments directly --
//   frag chunk (ks,q4) of row n is a contiguous 16B piece of latbf (prev/self/next row,
//   chunk q4&1) gathered per-lane, or a PE chunk (ks0,q4<2) read from a tiny 8 KB
//   intra-wave LDS buffer (same-wave write->read, NO barrier). Row idx distributed by
//   __shfl. The single __syncthreads (W2s DMA visibility) moves to AFTER GEMM1, so
//   phase-0 gather latency never sits behind a whole-WG drain (R6-R14's serializer).
// (256,2): tighter bounds trigger the gfx950 50/50 arch/acc split + scratch spill
// (R4/R5/R12: reported VGPR == budget/2, WRITE_SIZE 59-700 MB).
__global__ __launch_bounds__(256, 2) void lisagon_main(
    const float* __restrict__ coord, const unsigned short* __restrict__ latbf,
    const unsigned short* __restrict__ W1f, const unsigned short* __restrict__ W2f,
    const float* __restrict__ b2, const float* __restrict__ W3,
    const float* __restrict__ b3, float* __restrict__ out) {
  __shared__ __align__(16) unsigned short W2s[16384];      // 32 KB W2 fragments
  __shared__ __align__(16) unsigned PE[2][256][4];         // 8 KB: 2 planes x 256 rows x 16B
  __shared__ __align__(16) float BW[256];                  // b2 [0,128) | W3 [128,256)

  const int t = threadIdx.x;
  const int lane = t & 63, wv = t >> 6;
  const int l15 = lane & 15, q4 = lane >> 4;

  // ---- issue W2f -> LDS DMA first (covered until the post-GEMM1 barrier) ----
#pragma unroll
  for (int it = 0; it < 8; it++) {
    int off = (it * 4 + wv) * 1024;          // bytes; wave-uniform LDS base
    g2lds16((const char*)W2f + off + lane * 16, (char*)W2s + off);
  }
  // ---- stage b2 / W3 into LDS (1 KB; visible after the barrier) ----
  if (t < 64) {
    ((float4*)BW)[t] = (t < 32) ? ((const float4*)b2)[t] : ((const float4*)W3)[t - 32];
  }
  // ---- preload all 16 W1f fragments into registers (L1/L2-hot) ----
  const s8v* W1fv = (const s8v*)W1f;
  s8v W1r[16];
#pragma unroll
  for (int i = 0; i < 16; i++) W1r[i] = W1fv[i * 64 + lane];

  // ---- phase 0 (lite): idx + area + PE for row t; NO latent traffic ----
  int idx;
  float area;
  {
    const int Rg = blockIdx.x * 256 + t;
    const int gq = Rg >> 1, p = Rg & 1;       // p=0 -> vx=-2 pass, p=1 -> vx=0 pass
    const float co = coord[gq];
    float c = (co + (p ? 0.0f : -0.000244140625f)) + 1e-6f;  // vx*rx exact
    c = fminf(fmaxf(c, -1.0f + 1e-6f), 1.0f - 1e-6f);
    double u = ((double)c * 8192.0 + 8191.0) * 0.5;          // exact searchsorted
    idx = (int)ceil(u);
    idx = min(max(idx, 0), 8191);
    float qc = ((float)(2 * idx + 1) - 8192.0f) * (1.0f / 8192.0f);  // exact grid[idx]
    float rel = (co - qc) * 8192.0f;
    area = fabsf(rel) + 1e-9f;
    float v[16];
    v[0] = rel;
    float f = rel;
#pragma unroll
    for (int i = 0; i < 6; i++) {
      v[1 + 2 * i] = __sinf(f);
      v[2 + 2 * i] = __cosf(f);
      f = f + f;                 // exact power-of-2 freqs
    }
    v[13] = 1.0f;                // bias-fold slot (W1f input dim 13 = b1)
    v[14] = 0.0f; v[15] = 0.0f;
    uint4 q0, q1;
    q0.x = pk2(v[0], v[1]);   q0.y = pk2(v[2], v[3]);
    q0.z = pk2(v[4], v[5]);   q0.w = pk2(v[6], v[7]);
    q1.x = pk2(v[8], v[9]);   q1.y = pk2(v[10], v[11]);
    q1.z = pk2(v[12], v[13]); q1.w = pk2(v[14], v[15]);
    ((uint4*)PE[0])[t] = q0;   // plane 0: values 0..7 of row t
    ((uint4*)PE[1])[t] = q1;   // plane 1: values 8..15
  }

  // ---- per-lane direct B-fragment assembly (intra-wave only; NO barrier) ----
  // chunk map (== old A1 chunk ks*4+q4): ks0: q4<2 -> PE plane q4; q4>=2 -> prev,
  // chunk q4&1. ks1: q4<2 -> self, chunk q4&1; q4>=2 -> next, chunk q4&1.
  const size_t bbase = (size_t)(blockIdx.x >> 9) * (8192 * 16);   // batch, WG-uniform
  const uint4* latv4 = (const uint4*)(latbf + bbase);   // row r chunk c = latv4[r*2+c]
  const int rbase = wv * 64;
  s8v Bf[2][4];
#pragma unroll
  for (int rt = 0; rt < 4; rt++) {
    int srcl = rt * 16 + l15;                // source lane (same wave) for this row
    int sidx = __shfl(idx, srcl, 64);
    int rp = max(sidx - 1, 0), rn = min(sidx + 1, 8191);
    int c = q4 & 1;
    uint4 g0 = latv4[rp * 2 + c];                        // ks0 chunk (q4>=2; dummy else)
    uint4 g1 = latv4[(q4 < 2 ? sidx : rn) * 2 + c];      // ks1 chunk
    uint4 pe = ((const uint4*)PE[c])[rbase + srcl];      // PE chunk (q4<2; dummy else)
    uint4 b0;
    b0.x = q4 < 2 ? pe.x : g0.x;  b0.y = q4 < 2 ? pe.y : g0.y;
    b0.z = q4 < 2 ? pe.z : g0.z;  b0.w = q4 < 2 ? pe.w : g0.w;
    Bf[0][rt] = __builtin_bit_cast(s8v, b0);
    Bf[1][rt] = __builtin_bit_cast(s8v, g1);
  }

  // ---- GEMM1' (h-outer): one h-tile acc live; relu+pack DIRECTLY into bbv lanes ----
  // bbv[rt][ks] is GEMM2's B-fragment for K-chunk ks (K-permuted to match W2f):
  //   lane 2h'+half holds packed pair from GEMM1 output h = 2ks+h', half in {0,1}.
  u4v bbv[4][4];
#pragma unroll
  for (int h = 0; h < 8; h++) {
    f4v a[4];
#pragma unroll
    for (int rt = 0; rt < 4; rt++) a[rt] = (f4v){0.f, 0.f, 0.f, 0.f};
#pragma unroll
    for (int ks = 0; ks < 2; ks++) {
#pragma unroll
      for (int rt = 0; rt < 4; rt++)
        a[rt] = __builtin_amdgcn_mfma_f32_16x16x32_bf16(W1r[h * 2 + ks], Bf[ks][rt],
                                                        a[rt], 0, 0, 0);
    }
#pragma unroll
    for (int rt = 0; rt < 4; rt++) {
      bbv[rt][h >> 1][2 * (h & 1)]     = pk2(fmaxf(a[rt][0], 0.f), fmaxf(a[rt][1], 0.f));
      bbv[rt][h >> 1][2 * (h & 1) + 1] = pk2(fmaxf(a[rt][2], 0.f), fmaxf(a[rt][3], 0.f));
    }
  }

  __syncthreads();   // W2s DMA + BW visibility (full drain; GEMM1 already consumed Bf)

  // ---- GEMM2' (h2-outer, weights from LDS): b2 as acc-init; consume into dot ----
  const s8v* W2sv = (const s8v*)W2s;
  float s[4] = {0.f, 0.f, 0.f, 0.f};
#pragma unroll
  for (int h2 = 0; h2 < 8; h2++) {
    f4v a2[4];
    f4v b2v = ((const f4v*)BW)[h2 * 4 + q4];   // LDS broadcast; elem i -> h2dim 16h2+4q4+i
#pragma unroll
    for (int rt = 0; rt < 4; rt++) a2[rt] = b2v;
#pragma unroll
    for (int ks = 0; ks < 4; ks++) {
      s8v Af = W2sv[(h2 * 4 + ks) * 64 + lane];   // ds_read_b128, conflict-free
#pragma unroll
      for (int rt = 0; rt < 4; rt++)
        a2[rt] = __builtin_amdgcn_mfma_f32_16x16x32_bf16(
            Af, __builtin_bit_cast(s8v, bbv[rt][ks]), a2[rt], 0, 0, 0);
    }
    float4 w3v = ((const float4*)(BW + 128))[h2 * 4 + q4];   // LDS broadcast
#pragma unroll
    for (int rt = 0; rt < 4; rt++) {
      s[rt] += fmaxf(a2[rt][0], 0.f) * w3v.x;
      s[rt] += fmaxf(a2[rt][1], 0.f) * w3v.y;
      s[rt] += fmaxf(a2[rt][2], 0.f) * w3v.z;
      s[rt] += fmaxf(a2[rt][3], 0.f) * w3v.w;
    }
  }

  // ---- layer-3 reduce + local-ensemble combine (area via same-wave shfl) ----
  const float b3s = b3[0];
#pragma unroll
  for (int rt = 0; rt < 4; rt++) {
    float pred = s[rt];
    pred += __shfl_xor(pred, 16, 64);
    pred += __shfl_xor(pred, 32, 64);
    pred += b3s;
    float other = __shfl_xor(pred, 1, 64);   // (pass0, pass1) at adjacent l15
    float a0 = __shfl(area, rt * 16 + l15, 64);       // rows live in this wave
    float a1 = __shfl(area, rt * 16 + l15 + 1, 64);
    if (q4 == 0 && (l15 & 1) == 0) {
      int row0 = rbase + rt * 16 + l15;
      float tot = a0 + a1;
      // local_ensemble swap: pred(vx=-2)*a1/tot + pred(vx=0)*a0/tot
      out[(blockIdx.x * 256 + row0) >> 1] = pred * (a1 / tot) + other * (a0 / tot);
    }
  }
}

extern "C" void kernel_launch(void* const* d_in, const int* in_sizes, int n_in,
                              void* d_out, int out_size, void* d_ws, size_t ws_size,
                              hipStream_t stream) {
  const float* coord  = (const float*)d_in[0];
  const float* latent = (const float*)d_in[1];
  const float* W1 = (const float*)d_in[2];
  const float* b1 = (const float*)d_in[3];
  const float* W2 = (const float*)d_in[4];
  const float* b2 = (const float*)d_in[5];
  const float* W3 = (const float*)d_in[6];
  const float* b3 = (const float*)d_in[7];
  float* out = (float*)d_out;
  unsigned short* wsW = (unsigned short*)d_ws;   // W1f | W2f | latbf

  prep_kernel<<<2144, 256, 0, stream>>>(W1, b1, W2, latent, wsW);
  lisagon_main<<<2048, 256, 0, stream>>>(coord, wsW + 24576, wsW, wsW + 8192,
                                         b2, W3, b3, out);
}